// Round 1
// baseline (657.809 us; speedup 1.0000x reference)
//
#include <hip/hip_runtime.h>
#include <hip/hip_bf16.h>
#include <stdint.h>
#include <stddef.h>

typedef __attribute__((ext_vector_type(8))) short short8;
typedef __attribute__((ext_vector_type(4))) float floatx4;

#define GLDS16(gptr, lptr)                                                         \
  __builtin_amdgcn_global_load_lds(                                                \
      (const __attribute__((address_space(1))) void*)(gptr),                       \
      (__attribute__((address_space(3))) void*)(lptr), 16, 0, 0)

#define MTOT  100352   // 2048*49 tokens, = 784*128
#define KDIM  384
#define NQKV  1152
#define NPROJ 384

// ---------------------------------------------------------------------------
// fp32 -> bf16 convert (4 elems/thread)
// ---------------------------------------------------------------------------
__global__ void cvt_kernel(const float* __restrict__ in,
                           __hip_bfloat16* __restrict__ out, int n4) {
    int i = blockIdx.x * blockDim.x + threadIdx.x;
    if (i >= n4) return;
    float4 v = ((const float4*)in)[i];
    __hip_bfloat16* o = out + (size_t)i * 4;
    o[0] = __float2bfloat16(v.x);
    o[1] = __float2bfloat16(v.y);
    o[2] = __float2bfloat16(v.z);
    o[3] = __float2bfloat16(v.w);
}

// ---------------------------------------------------------------------------
// combined[h][w][n][m] = rel_bias_table[relidx(n,m)][h] + mask[w][n][m]
// total 12*64*2401 floats
// ---------------------------------------------------------------------------
__global__ void build_bias_kernel(const float* __restrict__ tbl,
                                  const float* __restrict__ mask,
                                  float* __restrict__ combined) {
    int tid = blockIdx.x * 256 + threadIdx.x;
    if (tid >= 12 * 64 * 2401) return;
    int hw = tid / 2401;
    int nm = tid - hw * 2401;
    int h  = hw / 64;
    int w2 = hw - h * 64;
    int n = nm / 49;
    int m = nm - n * 49;
    int i1 = n / 7, j1 = n - i1 * 7;
    int i2 = m / 7, j2 = m - i2 * 7;
    int ridx = (i1 - i2 + 6) * 13 + (j1 - j2 + 6);
    combined[tid] = tbl[ridx * 12 + h] + mask[(size_t)w2 * 2401 + nm];
}

// ---------------------------------------------------------------------------
// C = A(MxK) * B(NxK)^T + bias, bf16 inputs, fp32 accum.
// EPI==0: qkv epilogue -> scatter bf16 into q(scaled)/k/v [b,h,n,d] slabs
// EPI==1: fp32 C += bias -> Cout (row-major MxN)
// 128x128 tile, BK=32, 4 waves, each wave 64x64 via 4x4 of 16x16x32 MFMA.
// ---------------------------------------------------------------------------
template <int EPI>
__global__ __launch_bounds__(256) void gemm_bt_kernel(
    const __hip_bfloat16* __restrict__ A, const __hip_bfloat16* __restrict__ B,
    const float* __restrict__ bias, float* __restrict__ Cout,
    __hip_bfloat16* __restrict__ qbuf, __hip_bfloat16* __restrict__ kbuf,
    __hip_bfloat16* __restrict__ vbuf, int N) {
    __shared__ __hip_bfloat16 sA[128 * 32];
    __shared__ __hip_bfloat16 sB[128 * 32];
    const int t = threadIdx.x;
    const int bm = blockIdx.x, bn = blockIdx.y;
    const int lane = t & 63;
    const int w = t >> 6;
    const int wm = w & 1, wn = w >> 1;
    const int quad = lane >> 4, l15 = lane & 15;
    const int srow = t >> 2;        // 0..63
    const int scol = (t & 3) << 3;  // 0,8,16,24

    const __hip_bfloat16* Ab = A + (size_t)bm * 128 * KDIM;
    const __hip_bfloat16* Bb = B + (size_t)bn * 128 * KDIM;

    const floatx4 fzero = {0.f, 0.f, 0.f, 0.f};
    floatx4 acc[4][4];
#pragma unroll
    for (int i = 0; i < 4; ++i)
#pragma unroll
        for (int j = 0; j < 4; ++j) acc[i][j] = fzero;

    for (int kk = 0; kk < KDIM; kk += 32) {
        GLDS16(Ab + (size_t)srow * KDIM + kk + scol, &sA[srow * 32 + scol]);
        GLDS16(Ab + (size_t)(srow + 64) * KDIM + kk + scol,
               &sA[(srow + 64) * 32 + scol]);
        GLDS16(Bb + (size_t)srow * KDIM + kk + scol, &sB[srow * 32 + scol]);
        GLDS16(Bb + (size_t)(srow + 64) * KDIM + kk + scol,
               &sB[(srow + 64) * 32 + scol]);
        __syncthreads();
        short8 af[4], bf[4];
#pragma unroll
        for (int i = 0; i < 4; ++i)
            af[i] = *(const short8*)&sA[(wm * 64 + i * 16 + l15) * 32 + quad * 8];
#pragma unroll
        for (int j = 0; j < 4; ++j)
            bf[j] = *(const short8*)&sB[(wn * 64 + j * 16 + l15) * 32 + quad * 8];
#pragma unroll
        for (int i = 0; i < 4; ++i)
#pragma unroll
            for (int j = 0; j < 4; ++j)
                acc[i][j] = __builtin_amdgcn_mfma_f32_16x16x32_bf16(
                    af[i], bf[j], acc[i][j], 0, 0, 0);
        __syncthreads();
    }

    if (EPI == 0) {
        const float scale = 0.17677669529663687f;  // 1/sqrt(32)
#pragma unroll
        for (int j = 0; j < 4; ++j) {
            const int col = bn * 128 + wn * 64 + j * 16 + l15;  // 0..1151
            const int part = col / 384;
            const int within = col - part * 384;
            const int hh = within >> 5;
            const int d = within & 31;
            __hip_bfloat16* dst = (part == 0) ? qbuf : ((part == 1) ? kbuf : vbuf);
            const float bv = bias[col];
            const float mul = (part == 0) ? scale : 1.0f;
#pragma unroll
            for (int i = 0; i < 4; ++i) {
#pragma unroll
                for (int r = 0; r < 4; ++r) {
                    const int row = bm * 128 + wm * 64 + i * 16 + quad * 4 + r;
                    const int b = row / 49;
                    const int nn = row - b * 49;
                    const float val = (acc[i][j][r] + bv) * mul;
                    dst[(((size_t)b * 12 + hh) * 49 + nn) * 32 + d] =
                        __float2bfloat16(val);
                }
            }
        }
    } else {
#pragma unroll
        for (int j = 0; j < 4; ++j) {
            const int col = bn * 128 + wn * 64 + j * 16 + l15;
            const float bv = bias[col];
#pragma unroll
            for (int i = 0; i < 4; ++i) {
#pragma unroll
                for (int r = 0; r < 4; ++r) {
                    const int row = bm * 128 + wm * 64 + i * 16 + quad * 4 + r;
                    Cout[(size_t)row * N + col] = acc[i][j][r] + bv;
                }
            }
        }
    }
}

// ---------------------------------------------------------------------------
// attention: one wave per (b_, h). N=49 padded to 64, D=32.
// S = Q*K^T (scale pre-folded into Q) + combined[h, b_%64]; softmax;
// P -> LDS (C-layout -> A-layout re-map); O = P*V; store bf16 (token, h*32+d).
// ---------------------------------------------------------------------------
__global__ __launch_bounds__(64) void attn_kernel(
    const __hip_bfloat16* __restrict__ qbuf,
    const __hip_bfloat16* __restrict__ kbuf,
    const __hip_bfloat16* __restrict__ vbuf,
    const float* __restrict__ combined,
    __hip_bfloat16* __restrict__ attn_out) {
    __shared__ __hip_bfloat16 sP[64 * 64];
    const int id = blockIdx.x;
    const int h = id % 12;
    const int b_ = id / 12;
    const int wdx = b_ & 63;
    const int lane = threadIdx.x;
    const int quad = lane >> 4, l15 = lane & 15;
    const size_t base = (size_t)(b_ * 12 + h) * (49 * 32);
    const short* qb = (const short*)qbuf + base;
    const short* kb = (const short*)kbuf + base;
    const short* vb = (const short*)vbuf + base;

    const floatx4 fzero = {0.f, 0.f, 0.f, 0.f};

    short8 aQ[4], bK[4];
#pragma unroll
    for (int i = 0; i < 4; ++i) {
        int r = i * 16 + l15;
        r = r > 48 ? 48 : r;
        aQ[i] = *(const short8*)(qb + r * 32 + quad * 8);
    }
#pragma unroll
    for (int j = 0; j < 4; ++j) {
        int n = j * 16 + l15;
        n = n > 48 ? 48 : n;
        bK[j] = *(const short8*)(kb + n * 32 + quad * 8);
    }

    floatx4 S[4][4];
#pragma unroll
    for (int i = 0; i < 4; ++i)
#pragma unroll
        for (int j = 0; j < 4; ++j)
            S[i][j] =
                __builtin_amdgcn_mfma_f32_16x16x32_bf16(aQ[i], bK[j], fzero, 0, 0, 0);

    const float* cb = combined + (size_t)(h * 64 + wdx) * 2401;
#pragma unroll
    for (int i = 0; i < 4; ++i) {
#pragma unroll
        for (int r = 0; r < 4; ++r) {
            const int row = i * 16 + quad * 4 + r;
            float v0[4];
#pragma unroll
            for (int j = 0; j < 4; ++j) {
                const int col = j * 16 + l15;
                float s = S[i][j][r];
                if (row < 49 && col < 49)
                    s += cb[row * 49 + col];
                else
                    s = -1e30f;
                v0[j] = s;
            }
            float mx = fmaxf(fmaxf(v0[0], v0[1]), fmaxf(v0[2], v0[3]));
#pragma unroll
            for (int off = 8; off > 0; off >>= 1) mx = fmaxf(mx, __shfl_xor(mx, off));
            float sum = 0.f;
#pragma unroll
            for (int j = 0; j < 4; ++j) {
                v0[j] = __expf(v0[j] - mx);
                sum += v0[j];
            }
#pragma unroll
            for (int off = 8; off > 0; off >>= 1) sum += __shfl_xor(sum, off);
            const float inv = 1.0f / sum;
#pragma unroll
            for (int j = 0; j < 4; ++j)
                sP[row * 64 + j * 16 + l15] = __float2bfloat16(v0[j] * inv);
        }
    }
    __syncthreads();

    short8 aP[4][2];
#pragma unroll
    for (int i = 0; i < 4; ++i)
#pragma unroll
        for (int kk = 0; kk < 2; ++kk)
            aP[i][kk] =
                *(const short8*)&sP[(i * 16 + l15) * 64 + kk * 32 + quad * 8];

    short8 bV[2][2];
#pragma unroll
    for (int jd = 0; jd < 2; ++jd)
#pragma unroll
        for (int kk = 0; kk < 2; ++kk) {
            short8 tmp;
#pragma unroll
            for (int jj = 0; jj < 8; ++jj) {
                int k = kk * 32 + quad * 8 + jj;
                k = k > 48 ? 48 : k;
                tmp[jj] = vb[k * 32 + jd * 16 + l15];
            }
            bV[jd][kk] = tmp;
        }

    floatx4 O[4][2];
#pragma unroll
    for (int i = 0; i < 4; ++i)
#pragma unroll
        for (int jd = 0; jd < 2; ++jd) {
            floatx4 o = __builtin_amdgcn_mfma_f32_16x16x32_bf16(aP[i][0], bV[jd][0],
                                                                fzero, 0, 0, 0);
            o = __builtin_amdgcn_mfma_f32_16x16x32_bf16(aP[i][1], bV[jd][1], o, 0, 0,
                                                        0);
            O[i][jd] = o;
        }

#pragma unroll
    for (int i = 0; i < 4; ++i) {
#pragma unroll
        for (int r = 0; r < 4; ++r) {
            const int row = i * 16 + quad * 4 + r;
            if (row < 49) {
#pragma unroll
                for (int jd = 0; jd < 2; ++jd) {
                    attn_out[((size_t)b_ * 49 + row) * 384 + h * 32 + jd * 16 + l15] =
                        __float2bfloat16(O[i][jd][r]);
                }
            }
        }
    }
}

// ---------------------------------------------------------------------------
extern "C" void kernel_launch(void* const* d_in, const int* in_sizes, int n_in,
                              void* d_out, int out_size, void* d_ws,
                              size_t ws_size, hipStream_t stream) {
    (void)in_sizes; (void)n_in; (void)out_size; (void)ws_size;
    const float* x      = (const float*)d_in[0];
    const float* mask   = (const float*)d_in[1];
    const float* qkv_w  = (const float*)d_in[2];
    const float* qkv_b  = (const float*)d_in[3];
    const float* proj_w = (const float*)d_in[4];
    const float* proj_b = (const float*)d_in[5];
    const float* tbl    = (const float*)d_in[6];
    float* out = (float*)d_out;
    char* ws = (char*)d_ws;

    // workspace layout (bytes):
    //   x_bf / attn_out (aliased): 100352*384*2 = 77,070,336
    //   wq_bf: 1152*384*2 =   884,736   @ 77,070,336
    //   wp_bf:  384*384*2 =   294,912   @ 77,955,072
    //   combined: 12*64*2401*4 = 7,375,872 @ 78,249,984
    //   q_buf: 77,070,336 @  85,625,856
    //   k_buf: 77,070,336 @ 162,696,192
    //   v_buf: 77,070,336 @ 239,766,528   (end 316,836,864)
    __hip_bfloat16* x_bf    = (__hip_bfloat16*)(ws);
    __hip_bfloat16* wq_bf   = (__hip_bfloat16*)(ws + 77070336);
    __hip_bfloat16* wp_bf   = (__hip_bfloat16*)(ws + 77955072);
    float*          combined = (float*)(ws + 78249984);
    __hip_bfloat16* q_buf   = (__hip_bfloat16*)(ws + 85625856);
    __hip_bfloat16* k_buf   = (__hip_bfloat16*)(ws + 162696192);
    __hip_bfloat16* v_buf   = (__hip_bfloat16*)(ws + 239766528);
    __hip_bfloat16* attn_out = x_bf;  // x_bf dead after qkv gemm

    cvt_kernel<<<(MTOT * KDIM / 4 + 255) / 256, 256, 0, stream>>>(x, x_bf,
                                                                  MTOT * KDIM / 4);
    cvt_kernel<<<(NQKV * KDIM / 4 + 255) / 256, 256, 0, stream>>>(
        qkv_w, wq_bf, NQKV * KDIM / 4);
    cvt_kernel<<<(NPROJ * KDIM / 4 + 255) / 256, 256, 0, stream>>>(
        proj_w, wp_bf, NPROJ * KDIM / 4);
    build_bias_kernel<<<(12 * 64 * 2401 + 255) / 256, 256, 0, stream>>>(tbl, mask,
                                                                        combined);
    gemm_bt_kernel<0><<<dim3(MTOT / 128, NQKV / 128), 256, 0, stream>>>(
        x_bf, wq_bf, qkv_b, nullptr, q_buf, k_buf, v_buf, NQKV);
    attn_kernel<<<2048 * 12, 64, 0, stream>>>(q_buf, k_buf, v_buf, combined,
                                              attn_out);
    gemm_bt_kernel<1><<<dim3(MTOT / 128, NPROJ / 128), 256, 0, stream>>>(
        attn_out, wp_bf, proj_b, out, nullptr, nullptr, nullptr, NPROJ);
}

// Round 2
// 612.544 us; speedup vs baseline: 1.0739x; 1.0739x over previous
//
#include <hip/hip_runtime.h>
#include <hip/hip_bf16.h>
#include <stdint.h>
#include <stddef.h>

typedef __attribute__((ext_vector_type(8))) short short8;
typedef __attribute__((ext_vector_type(4))) float floatx4;

#define GLDS16(gptr, lptr)                                                         \
  __builtin_amdgcn_global_load_lds(                                                \
      (const __attribute__((address_space(1))) void*)(gptr),                       \
      (__attribute__((address_space(3))) void*)(lptr), 16, 0, 0)

#define MTOT  100352   // 2048*49 tokens, = 784*128
#define KDIM  384
#define NQKV  1152
#define NPROJ 384

static __device__ __forceinline__ unsigned short bfu(float f) {
    __hip_bfloat16 h = __float2bfloat16(f);
    return *(unsigned short*)&h;
}

// ---------------------------------------------------------------------------
// fp32 -> bf16 convert (4 elems/thread)
// ---------------------------------------------------------------------------
__global__ void cvt_kernel(const float* __restrict__ in,
                           __hip_bfloat16* __restrict__ out, int n4) {
    int i = blockIdx.x * blockDim.x + threadIdx.x;
    if (i >= n4) return;
    float4 v = ((const float4*)in)[i];
    __hip_bfloat16* o = out + (size_t)i * 4;
    o[0] = __float2bfloat16(v.x);
    o[1] = __float2bfloat16(v.y);
    o[2] = __float2bfloat16(v.z);
    o[3] = __float2bfloat16(v.w);
}

// ---------------------------------------------------------------------------
// comb[h][w][row(49)][52]: col<49 -> tbl+mask ; col>=49 -> -1e30
// ---------------------------------------------------------------------------
__global__ void build_bias_kernel(const float* __restrict__ tbl,
                                  const float* __restrict__ mask,
                                  float* __restrict__ comb) {
    int tid = blockIdx.x * 256 + threadIdx.x;
    if (tid >= 12 * 64 * 49 * 52) return;
    int hw = tid / 2548;
    int nm = tid - hw * 2548;
    int row = nm / 52;
    int col = nm - row * 52;
    int h = hw >> 6;
    int w2 = hw & 63;
    float v = -1e30f;
    if (col < 49) {
        int i1 = row / 7, j1 = row - i1 * 7;
        int i2 = col / 7, j2 = col - i2 * 7;
        int ridx = (i1 - i2 + 6) * 13 + (j1 - j2 + 6);
        v = tbl[ridx * 12 + h] + mask[(size_t)w2 * 2401 + row * 49 + col];
    }
    comb[tid] = v;
}

// ---------------------------------------------------------------------------
// C = A(MxK) * B(NxK)^T + bias.  128x128 tile, BK=64, XOR col-swizzled LDS.
// Grid: 1-D, L2-chunked: 16 M-tiles x NBN N-tiles per chunk.
// EPI==0: qkv epilogue (q scaled; v optionally transposed)   EPI==1: fp32 out
// ---------------------------------------------------------------------------
template <int EPI>
__global__ __launch_bounds__(256, 4) void gemm_bt_kernel(
    const __hip_bfloat16* __restrict__ A, const __hip_bfloat16* __restrict__ B,
    const float* __restrict__ bias, float* __restrict__ Cout,
    __hip_bfloat16* __restrict__ qbuf, __hip_bfloat16* __restrict__ kbuf,
    __hip_bfloat16* __restrict__ vbuf, int N, int NBN, int vt_mode) {
    __shared__ __hip_bfloat16 sA[128 * 64];
    __shared__ __hip_bfloat16 sB[128 * 64];
    const int t = threadIdx.x;
    const int per_chunk = 16 * NBN;
    const int chunk = blockIdx.x / per_chunk;
    const int rr = blockIdx.x - chunk * per_chunk;
    const int bn = rr >> 4;
    const int bm = chunk * 16 + (rr & 15);

    const int lane = t & 63;
    const int w = t >> 6;
    const int wm = w & 1, wn = w >> 1;
    const int quad = lane >> 4, l15 = lane & 15;
    const int srow = t >> 3;                 // 0..31
    const int scg = t & 7;                   // LDS col-group
    const int sg = scg ^ (srow & 7);         // swizzled global col-group
    const int rsw = l15 & 7;                 // read-side swizzle

    const __hip_bfloat16* Ab = A + (size_t)bm * 128 * KDIM;
    const __hip_bfloat16* Bb = B + (size_t)bn * 128 * KDIM;

    const floatx4 fzero = {0.f, 0.f, 0.f, 0.f};
    floatx4 acc[4][4];
#pragma unroll
    for (int i = 0; i < 4; ++i)
#pragma unroll
        for (int j = 0; j < 4; ++j) acc[i][j] = fzero;

    for (int kk = 0; kk < KDIM; kk += 64) {
#pragma unroll
        for (int i = 0; i < 4; ++i) {
            const int r0 = srow + i * 32;
            GLDS16(Ab + (size_t)r0 * KDIM + kk + sg * 8, &sA[r0 * 64 + scg * 8]);
            GLDS16(Bb + (size_t)r0 * KDIM + kk + sg * 8, &sB[r0 * 64 + scg * 8]);
        }
        __syncthreads();
#pragma unroll
        for (int kk2 = 0; kk2 < 2; ++kk2) {
            short8 af[4], bf[4];
#pragma unroll
            for (int i = 0; i < 4; ++i)
                af[i] = *(const short8*)&sA[(wm * 64 + i * 16 + l15) * 64 +
                                            ((kk2 * 4 + quad) ^ rsw) * 8];
#pragma unroll
            for (int j = 0; j < 4; ++j)
                bf[j] = *(const short8*)&sB[(wn * 64 + j * 16 + l15) * 64 +
                                            ((kk2 * 4 + quad) ^ rsw) * 8];
#pragma unroll
            for (int i = 0; i < 4; ++i)
#pragma unroll
                for (int j = 0; j < 4; ++j)
                    acc[i][j] = __builtin_amdgcn_mfma_f32_16x16x32_bf16(
                        af[i], bf[j], acc[i][j], 0, 0, 0);
        }
        __syncthreads();
    }

    int colv[4];
    float bv4[4];
#pragma unroll
    for (int j = 0; j < 4; ++j) {
        colv[j] = bn * 128 + wn * 64 + j * 16 + l15;
        bv4[j] = bias[colv[j]];
    }

    if (EPI == 0) {
        const float scale = 0.17677669529663687f;  // 1/sqrt(32)
        int partv[4], hv4[4], dv4[4];
#pragma unroll
        for (int j = 0; j < 4; ++j) {
            partv[j] = colv[j] >= 768 ? 2 : (colv[j] >= 384 ? 1 : 0);
            int within = colv[j] - partv[j] * 384;
            hv4[j] = within >> 5;
            dv4[j] = within & 31;
        }
#pragma unroll
        for (int i = 0; i < 4; ++i) {
#pragma unroll
            for (int r = 0; r < 4; ++r) {
                const int row = bm * 128 + wm * 64 + i * 16 + quad * 4 + r;
                const int b = row / 49;
                const int nn = row - b * 49;
#pragma unroll
                for (int j = 0; j < 4; ++j) {
                    const float val = acc[i][j][r] + bv4[j];
                    const size_t bh = (size_t)b * 12 + hv4[j];
                    if (partv[j] == 0)
                        qbuf[(bh * 49 + nn) * 32 + dv4[j]] =
                            __float2bfloat16(val * scale);
                    else if (partv[j] == 1)
                        kbuf[(bh * 49 + nn) * 32 + dv4[j]] = __float2bfloat16(val);
                    else {
                        if (vt_mode)
                            vbuf[(bh * 32 + dv4[j]) * 56 + nn] = __float2bfloat16(val);
                        else
                            vbuf[(bh * 49 + nn) * 32 + dv4[j]] = __float2bfloat16(val);
                    }
                }
            }
        }
    } else {
#pragma unroll
        for (int i = 0; i < 4; ++i) {
#pragma unroll
            for (int r = 0; r < 4; ++r) {
                const int row = bm * 128 + wm * 64 + i * 16 + quad * 4 + r;
#pragma unroll
                for (int j = 0; j < 4; ++j)
                    Cout[(size_t)row * N + colv[j]] = acc[i][j][r] + bv4[j];
            }
        }
    }
}

// ---------------------------------------------------------------------------
// attention, one wave per (b_, h).  S^T = K*Q^T so softmax rows live in-lane.
// VT=1: V^T global layout [b,h][d(32)][56] -> vector B-frag loads.
// ---------------------------------------------------------------------------
template <int VT>
__global__ __launch_bounds__(64) void attn_kernel(
    const __hip_bfloat16* __restrict__ qbuf,
    const __hip_bfloat16* __restrict__ kbuf,
    const __hip_bfloat16* __restrict__ vslab,
    const float* __restrict__ comb,
    __hip_bfloat16* __restrict__ attn_out) {
    __shared__ unsigned short sP[64 * 72];
    const int id = blockIdx.x;
    const int h = id >> 11;
    const int rem = id & 2047;
    const int w = rem >> 5;
    const int b = rem & 31;
    const int b_ = b * 64 + w;
    const int lane = threadIdx.x;
    const int quad = lane >> 4, l15 = lane & 15;
    const size_t bh = (size_t)b_ * 12 + h;
    const short* qb = (const short*)qbuf + bh * 1568;
    const short* kb = (const short*)kbuf + bh * 1568;
    const short* vb = (const short*)vslab + bh * (VT ? 1792 : 1568);

    const floatx4 fzero = {0.f, 0.f, 0.f, 0.f};

    short8 bQ[4], aK[4];
#pragma unroll
    for (int im = 0; im < 4; ++im) {
        int m = im * 16 + l15;
        m = m > 48 ? 48 : m;
        bQ[im] = *(const short8*)(qb + m * 32 + quad * 8);
    }
#pragma unroll
    for (int jn = 0; jn < 4; ++jn) {
        int n = jn * 16 + l15;
        n = n > 48 ? 48 : n;
        aK[jn] = *(const short8*)(kb + n * 32 + quad * 8);
    }

    // ST[im][jn][r] = S[m=im*16+l15][n=jn*16+quad*4+r]
    floatx4 ST[4][4];
#pragma unroll
    for (int im = 0; im < 4; ++im)
#pragma unroll
        for (int jn = 0; jn < 4; ++jn)
            ST[im][jn] = __builtin_amdgcn_mfma_f32_16x16x32_bf16(aK[jn], bQ[im],
                                                                 fzero, 0, 0, 0);

    const float* cb = comb + (size_t)(h * 64 + w) * 2548;
#pragma unroll
    for (int im = 0; im < 4; ++im) {
        const int m = im * 16 + l15;
        const int mrow = m > 48 ? 48 : m;
        const float* rp = cb + mrow * 52;
        float v[16];
#pragma unroll
        for (int jn = 0; jn < 3; ++jn) {
            float4 c4 = *(const float4*)(rp + jn * 16 + quad * 4);
            v[jn * 4 + 0] = ST[im][jn][0] + c4.x;
            v[jn * 4 + 1] = ST[im][jn][1] + c4.y;
            v[jn * 4 + 2] = ST[im][jn][2] + c4.z;
            v[jn * 4 + 3] = ST[im][jn][3] + c4.w;
        }
        {
            const float s48 = rp[48];
            v[12] = (quad == 0) ? (ST[im][3][0] + s48) : -1e30f;
            v[13] = -1e30f;
            v[14] = -1e30f;
            v[15] = -1e30f;
        }
        float mx = v[0];
#pragma unroll
        for (int q = 1; q < 16; ++q) mx = fmaxf(mx, v[q]);
        mx = fmaxf(mx, __shfl_xor(mx, 16));
        mx = fmaxf(mx, __shfl_xor(mx, 32));
        float sum = 0.f;
#pragma unroll
        for (int q = 0; q < 16; ++q) {
            v[q] = __expf(v[q] - mx);
            sum += v[q];
        }
        sum += __shfl_xor(sum, 16);
        sum += __shfl_xor(sum, 32);
        const float inv = 1.0f / sum;
#pragma unroll
        for (int jn = 0; jn < 4; ++jn) {
            uint2 pk;
            pk.x = (unsigned int)bfu(v[jn * 4 + 0] * inv) |
                   ((unsigned int)bfu(v[jn * 4 + 1] * inv) << 16);
            pk.y = (unsigned int)bfu(v[jn * 4 + 2] * inv) |
                   ((unsigned int)bfu(v[jn * 4 + 3] * inv) << 16);
            *(uint2*)&sP[m * 72 + jn * 16 + quad * 4] = pk;
        }
    }
    __syncthreads();

    short8 aP[4][2];
#pragma unroll
    for (int im = 0; im < 4; ++im)
#pragma unroll
        for (int kk = 0; kk < 2; ++kk)
            aP[im][kk] =
                *(const short8*)&sP[(im * 16 + l15) * 72 + kk * 32 + quad * 8];

    short8 bV[2][2];
    if (VT) {
#pragma unroll
        for (int jd = 0; jd < 2; ++jd)
#pragma unroll
            for (int kk = 0; kk < 2; ++kk) {
                int n0 = kk * 32 + quad * 8;
                n0 = n0 > 48 ? 48 : n0;
                bV[jd][kk] = *(const short8*)(vb + (jd * 16 + l15) * 56 + n0);
            }
    } else {
#pragma unroll
        for (int jd = 0; jd < 2; ++jd)
#pragma unroll
            for (int kk = 0; kk < 2; ++kk) {
                short8 tmp;
#pragma unroll
                for (int jj = 0; jj < 8; ++jj) {
                    int k = kk * 32 + quad * 8 + jj;
                    k = k > 48 ? 48 : k;
                    tmp[jj] = vb[k * 32 + jd * 16 + l15];
                }
                bV[jd][kk] = tmp;
            }
    }

    floatx4 O[4][2];
#pragma unroll
    for (int im = 0; im < 4; ++im)
#pragma unroll
        for (int jd = 0; jd < 2; ++jd) {
            floatx4 o = __builtin_amdgcn_mfma_f32_16x16x32_bf16(aP[im][0], bV[jd][0],
                                                                fzero, 0, 0, 0);
            o = __builtin_amdgcn_mfma_f32_16x16x32_bf16(aP[im][1], bV[jd][1], o, 0,
                                                        0, 0);
            O[im][jd] = o;
        }

#pragma unroll
    for (int im = 0; im < 4; ++im) {
#pragma unroll
        for (int r = 0; r < 4; ++r) {
            const int m = im * 16 + quad * 4 + r;
            if (m < 49) {
#pragma unroll
                for (int jd = 0; jd < 2; ++jd)
                    attn_out[((size_t)b_ * 49 + m) * 384 + h * 32 + jd * 16 + l15] =
                        __float2bfloat16(O[im][jd][r]);
            }
        }
    }
}

// ---------------------------------------------------------------------------
extern "C" void kernel_launch(void* const* d_in, const int* in_sizes, int n_in,
                              void* d_out, int out_size, void* d_ws,
                              size_t ws_size, hipStream_t stream) {
    (void)in_sizes; (void)n_in; (void)out_size;
    const float* x      = (const float*)d_in[0];
    const float* mask   = (const float*)d_in[1];
    const float* qkv_w  = (const float*)d_in[2];
    const float* qkv_b  = (const float*)d_in[3];
    const float* proj_w = (const float*)d_in[4];
    const float* proj_b = (const float*)d_in[5];
    const float* tbl    = (const float*)d_in[6];
    float* out = (float*)d_out;
    char* ws = (char*)d_ws;

    // layout (bytes):
    //   [0, 77070336)          x_bf / attn_out (aliased)
    //   [77070336, 84897792)   comb (12*64*49*52*4=7827456); wq_bf (884736)
    //                          overlaps comb start — wq dead before comb built
    //   [84897792, 85192704)   wp_bf (294912)
    //   [85192704, 162263040)  q_buf
    //   [162263040, 239333376) k_buf
    //   [239333376, ...)       v slab: VT -> 88080384 (end 327413760)
    //                                  fallback n-major -> 77070336 (end 316403712)
    __hip_bfloat16* x_bf  = (__hip_bfloat16*)(ws);
    __hip_bfloat16* wq_bf = (__hip_bfloat16*)(ws + 77070336);
    float*          comb  = (float*)(ws + 77070336);
    __hip_bfloat16* wp_bf = (__hip_bfloat16*)(ws + 84897792);
    __hip_bfloat16* q_buf = (__hip_bfloat16*)(ws + 85192704);
    __hip_bfloat16* k_buf = (__hip_bfloat16*)(ws + 162263040);
    __hip_bfloat16* v_slab = (__hip_bfloat16*)(ws + 239333376);
    __hip_bfloat16* attn_out = x_bf;  // x_bf dead after qkv gemm

    const int vt = (ws_size >= (size_t)327413760) ? 1 : 0;

    cvt_kernel<<<(MTOT * KDIM / 4 + 255) / 256, 256, 0, stream>>>(x, x_bf,
                                                                  MTOT * KDIM / 4);
    cvt_kernel<<<(NQKV * KDIM / 4 + 255) / 256, 256, 0, stream>>>(
        qkv_w, wq_bf, NQKV * KDIM / 4);
    cvt_kernel<<<(NPROJ * KDIM / 4 + 255) / 256, 256, 0, stream>>>(
        proj_w, wp_bf, NPROJ * KDIM / 4);
    gemm_bt_kernel<0><<<784 * 9, 256, 0, stream>>>(x_bf, wq_bf, qkv_b, nullptr,
                                                   q_buf, k_buf, v_slab, NQKV, 9,
                                                   vt);
    build_bias_kernel<<<(12 * 64 * 49 * 52 + 255) / 256, 256, 0, stream>>>(
        tbl, mask, comb);
    if (vt)
        attn_kernel<1><<<2048 * 12, 64, 0, stream>>>(q_buf, k_buf, v_slab, comb,
                                                     attn_out);
    else
        attn_kernel<0><<<2048 * 12, 64, 0, stream>>>(q_buf, k_buf, v_slab, comb,
                                                     attn_out);
    gemm_bt_kernel<1><<<784 * 3, 256, 0, stream>>>(attn_out, wp_bf, proj_b, out,
                                                   nullptr, nullptr, nullptr,
                                                   NPROJ, 3, 0);
}

// Round 3
// 557.816 us; speedup vs baseline: 1.1793x; 1.0981x over previous
//
#include <hip/hip_runtime.h>
#include <hip/hip_bf16.h>
#include <stdint.h>
#include <stddef.h>

typedef __attribute__((ext_vector_type(8))) short short8;
typedef __attribute__((ext_vector_type(4))) float floatx4;

#define GLDS16(gptr, lptr)                                                         \
  __builtin_amdgcn_global_load_lds(                                                \
      (const __attribute__((address_space(1))) void*)(gptr),                       \
      (__attribute__((address_space(3))) void*)(lptr), 16, 0, 0)

#define MTOT  100352   // 2048*49 tokens, = 784*128
#define KDIM  384
#define NQKV  1152
#define NPROJ 384

static __device__ __forceinline__ unsigned int bfu(float f) {
    __hip_bfloat16 h = __float2bfloat16(f);
    return (unsigned int)*(unsigned short*)&h;
}

// ---------------------------------------------------------------------------
// fp32 -> bf16 convert (4 elems/thread)
// ---------------------------------------------------------------------------
__global__ void cvt_kernel(const float* __restrict__ in,
                           __hip_bfloat16* __restrict__ out, int n4) {
    int i = blockIdx.x * blockDim.x + threadIdx.x;
    if (i >= n4) return;
    float4 v = ((const float4*)in)[i];
    __hip_bfloat16* o = out + (size_t)i * 4;
    o[0] = __float2bfloat16(v.x);
    o[1] = __float2bfloat16(v.y);
    o[2] = __float2bfloat16(v.z);
    o[3] = __float2bfloat16(v.w);
}

// ---------------------------------------------------------------------------
// comb[h][w][row(49)][52]: col<49 -> tbl+mask ; col>=49 -> -1e30
// ---------------------------------------------------------------------------
__global__ void build_bias_kernel(const float* __restrict__ tbl,
                                  const float* __restrict__ mask,
                                  float* __restrict__ comb) {
    int tid = blockIdx.x * 256 + threadIdx.x;
    if (tid >= 12 * 64 * 49 * 52) return;
    int hw = tid / 2548;
    int nm = tid - hw * 2548;
    int row = nm / 52;
    int col = nm - row * 52;
    int h = hw >> 6;
    int w2 = hw & 63;
    float v = -1e30f;
    if (col < 49) {
        int i1 = row / 7, j1 = row - i1 * 7;
        int i2 = col / 7, j2 = col - i2 * 7;
        int ridx = (i1 - i2 + 6) * 13 + (j1 - j2 + 6);
        v = tbl[ridx * 12 + h] + mask[(size_t)w2 * 2401 + row * 49 + col];
    }
    comb[tid] = v;
}

// ---------------------------------------------------------------------------
// C = A(MxK) * B(NxK)^T + bias.  128x128 tile, BK=64, XOR col-swizzled LDS.
// Operand-SWAPPED MFMA: acc[i][j] holds C^T tile -> lane l15 = M-row (token),
// quad*4+r = 4 consecutive N-cols -> vectorized epilogue stores.
// EPI==0: bf16 out (q cols scaled by 1/sqrt(32)), uint2 (4xbf16) stores.
// EPI==1: fp32 out, float4 stores.
// ---------------------------------------------------------------------------
template <int EPI>
__global__ __launch_bounds__(256, 4) void gemm_bt_kernel(
    const __hip_bfloat16* __restrict__ A, const __hip_bfloat16* __restrict__ B,
    const float* __restrict__ bias, float* __restrict__ Cout,
    __hip_bfloat16* __restrict__ Cbf, int N, int NBN) {
    __shared__ __hip_bfloat16 sA[128 * 64];
    __shared__ __hip_bfloat16 sB[128 * 64];
    const int t = threadIdx.x;
    const int per_chunk = 16 * NBN;
    const int chunk = blockIdx.x / per_chunk;
    const int rr = blockIdx.x - chunk * per_chunk;
    const int bn = rr >> 4;
    const int bm = chunk * 16 + (rr & 15);

    const int lane = t & 63;
    const int w = t >> 6;
    const int wm = w & 1, wn = w >> 1;
    const int quad = lane >> 4, l15 = lane & 15;
    const int srow = t >> 3;                 // 0..31
    const int scg = t & 7;                   // LDS col-group
    const int sg = scg ^ (srow & 7);         // swizzled global col-group
    const int rsw = l15 & 7;                 // read-side swizzle

    const __hip_bfloat16* Ab = A + (size_t)bm * 128 * KDIM;
    const __hip_bfloat16* Bb = B + (size_t)bn * 128 * KDIM;

    const floatx4 fzero = {0.f, 0.f, 0.f, 0.f};
    floatx4 acc[4][4];
#pragma unroll
    for (int i = 0; i < 4; ++i)
#pragma unroll
        for (int j = 0; j < 4; ++j) acc[i][j] = fzero;

    for (int kk = 0; kk < KDIM; kk += 64) {
#pragma unroll
        for (int i = 0; i < 4; ++i) {
            const int r0 = srow + i * 32;
            GLDS16(Ab + (size_t)r0 * KDIM + kk + sg * 8, &sA[r0 * 64 + scg * 8]);
            GLDS16(Bb + (size_t)r0 * KDIM + kk + sg * 8, &sB[r0 * 64 + scg * 8]);
        }
        __syncthreads();
#pragma unroll
        for (int kk2 = 0; kk2 < 2; ++kk2) {
            short8 af[4], bf[4];
#pragma unroll
            for (int i = 0; i < 4; ++i)
                af[i] = *(const short8*)&sA[(wm * 64 + i * 16 + l15) * 64 +
                                            ((kk2 * 4 + quad) ^ rsw) * 8];
#pragma unroll
            for (int j = 0; j < 4; ++j)
                bf[j] = *(const short8*)&sB[(wn * 64 + j * 16 + l15) * 64 +
                                            ((kk2 * 4 + quad) ^ rsw) * 8];
#pragma unroll
            for (int i = 0; i < 4; ++i)
#pragma unroll
                for (int j = 0; j < 4; ++j)
                    acc[i][j] = __builtin_amdgcn_mfma_f32_16x16x32_bf16(
                        bf[j], af[i], acc[i][j], 0, 0, 0);  // SWAPPED
        }
        __syncthreads();
    }

    // epilogue: lane = token row m; quad*4 = first of 4 consecutive cols
    if (EPI == 0) {
        const float scale = 0.17677669529663687f;  // 1/sqrt(32)
#pragma unroll
        for (int i = 0; i < 4; ++i) {
            const int m = bm * 128 + wm * 64 + i * 16 + l15;
#pragma unroll
            for (int j = 0; j < 4; ++j) {
                const int f0 = bn * 128 + wn * 64 + j * 16 + quad * 4;
                const float4 bv = *(const float4*)&bias[f0];
                const float sc = (f0 < 384) ? scale : 1.0f;
                uint2 pk;
                pk.x = bfu((acc[i][j][0] + bv.x) * sc) |
                       (bfu((acc[i][j][1] + bv.y) * sc) << 16);
                pk.y = bfu((acc[i][j][2] + bv.z) * sc) |
                       (bfu((acc[i][j][3] + bv.w) * sc) << 16);
                *(uint2*)&Cbf[(size_t)m * NQKV + f0] = pk;
            }
        }
    } else {
#pragma unroll
        for (int i = 0; i < 4; ++i) {
            const int m = bm * 128 + wm * 64 + i * 16 + l15;
#pragma unroll
            for (int j = 0; j < 4; ++j) {
                const int f0 = bn * 128 + wn * 64 + j * 16 + quad * 4;
                const float4 bv = *(const float4*)&bias[f0];
                float4 o;
                o.x = acc[i][j][0] + bv.x;
                o.y = acc[i][j][1] + bv.y;
                o.z = acc[i][j][2] + bv.z;
                o.w = acc[i][j][3] + bv.w;
                *(float4*)&Cout[(size_t)m * N + f0] = o;
            }
        }
    }
}

// ---------------------------------------------------------------------------
// attention, one wave per (b_, h).  Reads q/k/v from row-major qkv (M x 1152).
// S^T = K*Q^T so softmax rows live in-lane.  V transposed via blocked LDS.
// O computed operand-swapped -> lane = token, 4 consecutive d -> uint2 stores.
// ---------------------------------------------------------------------------
__global__ __launch_bounds__(64) void attn_kernel(
    const __hip_bfloat16* __restrict__ qkv,
    const float* __restrict__ comb,
    __hip_bfloat16* __restrict__ attn_out) {
    __shared__ unsigned short sP[64 * 72];
    __shared__ unsigned short sVB[4][66][8];  // [d>>3][n][d&7]
    const int id = blockIdx.x;
    const int h = id >> 11;
    const int rem = id & 2047;
    const int w = rem >> 5;
    const int b = rem & 31;
    const int b_ = b * 64 + w;
    const int lane = threadIdx.x;
    const int quad = lane >> 4, l15 = lane & 15;
    const short* base = (const short*)qkv + (size_t)b_ * 49 * 1152 + h * 32;

    const floatx4 fzero = {0.f, 0.f, 0.f, 0.f};

    short8 bQ[4], aK[4];
#pragma unroll
    for (int im = 0; im < 4; ++im) {
        int m = im * 16 + l15;
        m = m > 48 ? 48 : m;
        bQ[im] = *(const short8*)(base + (size_t)m * 1152 + quad * 8);
    }
#pragma unroll
    for (int jn = 0; jn < 4; ++jn) {
        int n = jn * 16 + l15;
        n = n > 48 ? 48 : n;
        aK[jn] = *(const short8*)(base + (size_t)n * 1152 + 384 + quad * 8);
    }
    // V rows -> blocked LDS (zero the pad rows to avoid NaN garbage)
    const short8 zero8 = {0, 0, 0, 0, 0, 0, 0, 0};
#pragma unroll
    for (int jn = 0; jn < 4; ++jn) {
        const int n = jn * 16 + l15;
        const int nc = n > 48 ? 48 : n;
        short8 vv = *(const short8*)(base + (size_t)nc * 1152 + 768 + quad * 8);
        if (n > 48) vv = zero8;
        *(short8*)&sVB[quad][n][0] = vv;
    }

    // ST[im][jn][r] = S[m=im*16+l15][n=jn*16+quad*4+r]
    floatx4 ST[4][4];
#pragma unroll
    for (int im = 0; im < 4; ++im)
#pragma unroll
        for (int jn = 0; jn < 4; ++jn)
            ST[im][jn] = __builtin_amdgcn_mfma_f32_16x16x32_bf16(aK[jn], bQ[im],
                                                                 fzero, 0, 0, 0);

    const float* cb = comb + (size_t)(h * 64 + w) * 2548;
#pragma unroll
    for (int im = 0; im < 4; ++im) {
        const int m = im * 16 + l15;
        const int mrow = m > 48 ? 48 : m;
        const float* rp = cb + mrow * 52;
        float v[16];
#pragma unroll
        for (int jn = 0; jn < 3; ++jn) {
            float4 c4 = *(const float4*)(rp + jn * 16 + quad * 4);
            v[jn * 4 + 0] = ST[im][jn][0] + c4.x;
            v[jn * 4 + 1] = ST[im][jn][1] + c4.y;
            v[jn * 4 + 2] = ST[im][jn][2] + c4.z;
            v[jn * 4 + 3] = ST[im][jn][3] + c4.w;
        }
        {
            const float s48 = rp[48];
            v[12] = (quad == 0) ? (ST[im][3][0] + s48) : -1e30f;
            v[13] = -1e30f;
            v[14] = -1e30f;
            v[15] = -1e30f;
        }
        float mx = v[0];
#pragma unroll
        for (int q = 1; q < 16; ++q) mx = fmaxf(mx, v[q]);
        mx = fmaxf(mx, __shfl_xor(mx, 16));
        mx = fmaxf(mx, __shfl_xor(mx, 32));
        float sum = 0.f;
#pragma unroll
        for (int q = 0; q < 16; ++q) {
            v[q] = __expf(v[q] - mx);
            sum += v[q];
        }
        sum += __shfl_xor(sum, 16);
        sum += __shfl_xor(sum, 32);
        const float inv = 1.0f / sum;
#pragma unroll
        for (int jn = 0; jn < 4; ++jn) {
            uint2 pk;
            pk.x = bfu(v[jn * 4 + 0] * inv) | (bfu(v[jn * 4 + 1] * inv) << 16);
            pk.y = bfu(v[jn * 4 + 2] * inv) | (bfu(v[jn * 4 + 3] * inv) << 16);
            *(uint2*)&sP[m * 72 + jn * 16 + quad * 4] = pk;
        }
    }
    __syncthreads();

    short8 aP[4][2];
#pragma unroll
    for (int im = 0; im < 4; ++im)
#pragma unroll
        for (int kk = 0; kk < 2; ++kk)
            aP[im][kk] =
                *(const short8*)&sP[(im * 16 + l15) * 72 + kk * 32 + quad * 8];

    short8 bV[2][2];
#pragma unroll
    for (int jd = 0; jd < 2; ++jd) {
        const int d = jd * 16 + l15;
        const int db = d >> 3, dl = d & 7;
#pragma unroll
        for (int kk = 0; kk < 2; ++kk) {
            short8 tmp;
#pragma unroll
            for (int jj = 0; jj < 8; ++jj)
                tmp[jj] = (short)sVB[db][kk * 32 + quad * 8 + jj][dl];
            bV[jd][kk] = tmp;
        }
    }

    // O^T tiles: row = d (quad*4+r consecutive), col = token m = l15
    floatx4 O[4][2];
#pragma unroll
    for (int im = 0; im < 4; ++im)
#pragma unroll
        for (int jd = 0; jd < 2; ++jd) {
            floatx4 o = __builtin_amdgcn_mfma_f32_16x16x32_bf16(bV[jd][0],
                                                                aP[im][0], fzero,
                                                                0, 0, 0);
            o = __builtin_amdgcn_mfma_f32_16x16x32_bf16(bV[jd][1], aP[im][1], o, 0,
                                                        0, 0);
            O[im][jd] = o;
        }

#pragma unroll
    for (int im = 0; im < 4; ++im) {
        const int m = im * 16 + l15;
        if (m < 49) {
#pragma unroll
            for (int jd = 0; jd < 2; ++jd) {
                uint2 pk;
                pk.x = bfu(O[im][jd][0]) | (bfu(O[im][jd][1]) << 16);
                pk.y = bfu(O[im][jd][2]) | (bfu(O[im][jd][3]) << 16);
                *(uint2*)&attn_out[((size_t)b_ * 49 + m) * 384 + h * 32 +
                                   jd * 16 + quad * 4] = pk;
            }
        }
    }
}

// ---------------------------------------------------------------------------
extern "C" void kernel_launch(void* const* d_in, const int* in_sizes, int n_in,
                              void* d_out, int out_size, void* d_ws,
                              size_t ws_size, hipStream_t stream) {
    (void)in_sizes; (void)n_in; (void)out_size; (void)ws_size;
    const float* x      = (const float*)d_in[0];
    const float* mask   = (const float*)d_in[1];
    const float* qkv_w  = (const float*)d_in[2];
    const float* qkv_b  = (const float*)d_in[3];
    const float* proj_w = (const float*)d_in[4];
    const float* proj_b = (const float*)d_in[5];
    const float* tbl    = (const float*)d_in[6];
    float* out = (float*)d_out;
    char* ws = (char*)d_ws;

    // layout (bytes), total 316,403,712 (<= round-1-proven 316,836,864):
    //   [0, 77070336)          x_bf / attn_out (aliased; x_bf dead after qkv)
    //   [77070336, 84897792)   comb (7,827,456); wq_bf (884,736) aliased at
    //                          start — wq dead before comb is built
    //   [84897792, 85192704)   wp_bf (294,912)
    //   [85192704, 316403712)  qkv_out row-major M x 1152 bf16 (231,211,008)
    __hip_bfloat16* x_bf   = (__hip_bfloat16*)(ws);
    __hip_bfloat16* wq_bf  = (__hip_bfloat16*)(ws + 77070336);
    float*          comb   = (float*)(ws + 77070336);
    __hip_bfloat16* wp_bf  = (__hip_bfloat16*)(ws + 84897792);
    __hip_bfloat16* qkv_o  = (__hip_bfloat16*)(ws + 85192704);
    __hip_bfloat16* attn_o = x_bf;

    cvt_kernel<<<(MTOT * KDIM / 4 + 255) / 256, 256, 0, stream>>>(x, x_bf,
                                                                  MTOT * KDIM / 4);
    cvt_kernel<<<(NQKV * KDIM / 4 + 255) / 256, 256, 0, stream>>>(
        qkv_w, wq_bf, NQKV * KDIM / 4);
    cvt_kernel<<<(NPROJ * KDIM / 4 + 255) / 256, 256, 0, stream>>>(
        proj_w, wp_bf, NPROJ * KDIM / 4);
    gemm_bt_kernel<0><<<784 * 9, 256, 0, stream>>>(x_bf, wq_bf, qkv_b, nullptr,
                                                   qkv_o, NQKV, 9);
    build_bias_kernel<<<(12 * 64 * 49 * 52 + 255) / 256, 256, 0, stream>>>(
        tbl, mask, comb);
    attn_kernel<<<2048 * 12, 64, 0, stream>>>(qkv_o, comb, attn_o);
    gemm_bt_kernel<1><<<784 * 3, 256, 0, stream>>>(attn_o, wp_bf, proj_b, out,
                                                   nullptr, NPROJ, 3);
}